// Round 7
// baseline (436.340 us; speedup 1.0000x reference)
//
#include <hip/hip_runtime.h>

#define SEQ_LEN 2048
#define BATCH   512
#define HIDDEN  25

typedef int v2i __attribute__((ext_vector_type(2)));
typedef _Float16 h2_t __attribute__((ext_vector_type(2)));

__device__ __forceinline__ float fast_rcp(float v)  { return __builtin_amdgcn_rcpf(v); }
__device__ __forceinline__ float fast_exp2(float v) { return __builtin_amdgcn_exp2f(v); }

// D = a.lo*b.lo + a.hi*b.hi + c, f16 multiply / f32 accumulate
__device__ __forceinline__ float fdot2i(int a, int b, float c) {
#if __has_builtin(__builtin_amdgcn_fdot2)
    return __builtin_amdgcn_fdot2(__builtin_bit_cast(h2_t, a), __builtin_bit_cast(h2_t, b), c, false);
#else
    float d;
    asm("v_dot2_f32_f16 %0, %1, %2, %3" : "=v"(d) : "v"(a), "v"(b), "v"(c));
    return d;
#endif
}

// Full lane<->lane^32 exchange, polarity-proof.
__device__ __forceinline__ float xswap32(float v) {
#if __has_builtin(__builtin_amdgcn_permlane32_swap)
    v2i r = __builtin_amdgcn_permlane32_swap(__float_as_int(v), __float_as_int(v), false, false);
    return (__int_as_float(r.x) + __int_as_float(r.y)) - v;
#else
    return __shfl_xor(v, 32);
#endif
}

// One wave per batch element.
//   L lane j  (0..24):  rows j (i, sigmoid) and 50+j (g, tanh)  -> i*g local
//   U lane 32+j (0..24): rows 25+j (f) and 75+j (o); owns c_j, h_j
// h crosses as PACKED f16 pairs; broadcast now via ds_bpermute (VGPR-only
// dataflow, no v_readlane->SGPR->VALU hazard nops / SGPR->VGPR movs). The 13
// bpermute addresses are loop-invariant, precomputed and pinned.
__global__ __launch_bounds__(64)
__attribute__((amdgpu_waves_per_eu(1, 1)))
void lstm_kernel(
    const float* __restrict__ x,
    const float* __restrict__ W_ih,
    const float* __restrict__ W_hh,
    const float* __restrict__ b_ih,
    const float* __restrict__ b_hh,
    const float* __restrict__ W_lin,
    const float* __restrict__ b_lin,
    float* __restrict__ out)
{
    const int lane = threadIdx.x;
    const int b    = blockIdx.x;

    __shared__ float pp[64][29];   // deferred output partials; 29 coprime w/ 32 banks

    const bool U  = (lane >= 32);
    const int  j  = lane & 31;
    const int  jj = (j < HIDDEN) ? j : 0;          // clamp idle lanes to a harmless row
    const bool hv = (j < HIDDEN);

    const int r1 = U ? (HIDDEN + jj) : jj;                     // f : i  (sigmoid)
    const int r2 = U ? (3 * HIDDEN + jj) : (2 * HIDDEN + jj);  // o : g

    const float LOG2E = 1.4426950408889634f;
    const float s1 = -LOG2E;                       // sigmoid pre-scale
    const float s2 = U ? -LOG2E : (-2.0f * LOG2E); // o: sigmoid, g: tanh(=sig(2x) form)

    // fold scales into weights, pad k=25 with 0, pack to f16 pairs
    float w1[26], w2[26];
    #pragma unroll
    for (int k = 0; k < HIDDEN; ++k) {
        w1[k] = W_hh[r1 * HIDDEN + k] * s1;
        w2[k] = W_hh[r2 * HIDDEN + k] * s2;
    }
    w1[25] = 0.0f; w2[25] = 0.0f;
    int W1p[13], W2p[13];
    #pragma unroll
    for (int m = 0; m < 13; ++m) {
        W1p[m] = __builtin_bit_cast(int, __builtin_amdgcn_cvt_pkrtz(w1[2*m], w1[2*m+1]));
        W2p[m] = __builtin_bit_cast(int, __builtin_amdgcn_cvt_pkrtz(w2[2*m], w2[2*m+1]));
    }
    float bias1 = (b_ih[r1] + b_hh[r1]) * s1;
    float bias2 = (b_ih[r2] + b_hh[r2]) * s2;
    float wi1   = W_ih[r1] * s1;
    float wi2   = W_ih[r2] * s2;

    // bpermute byte-addresses for the 13 packed-h source lanes (32, 34, ... 56)
    int baddr[13];
    #pragma unroll
    for (int m = 0; m < 13; ++m) baddr[m] = 4 * (32 + 2 * m);

    // pin loop-invariants into VGPRs (defeat remat/spill)
    #pragma unroll
    for (int m = 0; m < 13; ++m) {
        asm volatile("" : "+v"(W1p[m]));
        asm volatile("" : "+v"(W2p[m]));
        asm volatile("" : "+v"(baddr[m]));
    }
    asm volatile("" : "+v"(bias1), "+v"(bias2), "+v"(wi1), "+v"(wi2));

    const float wlin  = (U && hv) ? W_lin[jj] : 0.0f;
    const float blin  = b_lin[0];
    const int   pcol  = (U && hv) ? jj : 26;       // inactive lanes dump into unused col

    float cs = 0.0f;   // c' = -2log2e * c   (real on U lanes)
    float vh = 0.0f;   // h                  (real on U lanes)

    const float* xb = x + b;
    float xv = xb[(size_t)lane * BATCH];           // x[t=lane][b], staggered prefetch

    #pragma unroll 1
    for (int tb = 0; tb < SEQ_LEN; tb += 64) {
        float xv_next = 0.0f;
        if (tb + 64 < SEQ_LEN) xv_next = xb[(size_t)(tb + 64 + lane) * BATCH];

        #pragma unroll 4
        for (int tt = 0; tt < 64; ++tt) {
            // x-side affine (independent of h -> schedules into stall slots)
            const float xt = __int_as_float(__builtin_amdgcn_readlane(__float_as_int(xv), tt));
            float a1 = fmaf(xt, wi1, bias1);
            float a2 = fmaf(xt, wi2, bias2);

            // pack {h_j, h_{j^1}} as f16x2 (valid on even U lanes)
            const int vhn = __builtin_amdgcn_mov_dpp(__float_as_int(vh), 0xB1, 0xF, 0xF, true);
            const int hpk = __builtin_bit_cast(int,
                __builtin_amdgcn_cvt_pkrtz(vh, __int_as_float(vhn)));

            // broadcast 25 h values as 13 packed words via ds_bpermute (VGPR-only)
            int hw[13];
            #pragma unroll
            for (int m = 0; m < 13; ++m)
                hw[m] = __builtin_amdgcn_ds_bpermute(baddr[m], hpk);

            float b1 = 0.0f, b2 = 0.0f;
            #pragma unroll
            for (int m = 0; m < 12; m += 2) {      // 4 independent dot2 chains
                a1 = fdot2i(W1p[m],     hw[m],     a1);
                b1 = fdot2i(W1p[m + 1], hw[m + 1], b1);
                a2 = fdot2i(W2p[m],     hw[m],     a2);
                b2 = fdot2i(W2p[m + 1], hw[m + 1], b2);
            }
            a1 = fdot2i(W1p[12], hw[12], a1) + b1;
            a2 = fdot2i(W2p[12], hw[12], a2) + b2;

            const float R1 = fast_rcp(1.0f + fast_exp2(a1));   // i (L) / f (U)
            const float R2 = fast_rcp(1.0f + fast_exp2(a2));   // sig(2zg) (L) / o (U)

            // L: igs = i * g * (-2log2e), where g = 2*R2 - 1
            const float Gp  = fmaf(R2, -4.0f * LOG2E, 2.0f * LOG2E);
            const float igs = R1 * Gp;
            const float igx = xswap32(igs);        // U lanes receive L's igs

            cs = fmaf(R1, cs, igx);                // c' = f*c' + (-2log2e)*i*g  (U)
            const float R3 = fast_rcp(1.0f + fast_exp2(cs));   // sig(2c) -> tanh(c)=2R3-1
            const float o2 = R2 + R2;              // 2o (off critical path)
            vh = fmaf(o2, R3, -R2);                // h = o*tanh(c) = 2o*R3 - o  (U)

            pp[tt][pcol] = vh * wlin;              // deferred output partial
        }
        __syncthreads();

        // reduce 64 timesteps of output partials; one store per lane
        float s = blin;
        #pragma unroll
        for (int k = 0; k < HIDDEN; ++k) s += pp[lane][k];
        out[(size_t)(tb + lane) * BATCH + b] = s;
        __syncthreads();

        xv = xv_next;
    }
}

extern "C" void kernel_launch(void* const* d_in, const int* in_sizes, int n_in,
                              void* d_out, int out_size, void* d_ws, size_t ws_size,
                              hipStream_t stream) {
    const float* x     = (const float*)d_in[0];
    const float* W_ih  = (const float*)d_in[1];
    const float* W_hh  = (const float*)d_in[2];
    const float* b_ih  = (const float*)d_in[3];
    const float* b_hh  = (const float*)d_in[4];
    const float* W_lin = (const float*)d_in[5];
    const float* b_lin = (const float*)d_in[6];
    float* outp = (float*)d_out;

    hipLaunchKernelGGL(lstm_kernel, dim3(BATCH), dim3(64), 0, stream,
                       x, W_ih, W_hh, b_ih, b_hh, W_lin, b_lin, outp);
}

// Round 8
// 366.772 us; speedup vs baseline: 1.1897x; 1.1897x over previous
//
#include <hip/hip_runtime.h>

#define SEQ_LEN 2048
#define BATCH   512
#define HIDDEN  25

typedef int v2i __attribute__((ext_vector_type(2)));
typedef _Float16 h2_t __attribute__((ext_vector_type(2)));

__device__ __forceinline__ float fast_rcp(float v)  { return __builtin_amdgcn_rcpf(v); }
__device__ __forceinline__ float fast_exp2(float v) { return __builtin_amdgcn_exp2f(v); }

// D = a.lo*b.lo + a.hi*b.hi + c, f16 multiply / f32 accumulate
__device__ __forceinline__ float fdot2i(int a, int b, float c) {
#if __has_builtin(__builtin_amdgcn_fdot2)
    return __builtin_amdgcn_fdot2(__builtin_bit_cast(h2_t, a), __builtin_bit_cast(h2_t, b), c, false);
#else
    float d;
    asm("v_dot2_f32_f16 %0, %1, %2, %3" : "=v"(d) : "v"(a), "v"(b), "v"(c));
    return d;
#endif
}

// Full lane<->lane^32 exchange, polarity-proof.
__device__ __forceinline__ float xswap32(float v) {
#if __has_builtin(__builtin_amdgcn_permlane32_swap)
    v2i r = __builtin_amdgcn_permlane32_swap(__float_as_int(v), __float_as_int(v), false, false);
    return (__int_as_float(r.x) + __int_as_float(r.y)) - v;
#else
    return __shfl_xor(v, 32);
#endif
}

// One wave per batch element.
//   L lane j  (0..24):  rows j (i, sigmoid) and 50+j (g, tanh)  -> i*g local
//   U lane 32+j (0..24): rows 25+j (f) and 75+j (o); owns c_j, h_j
// h crosses as packed f16 pairs through LDS with ONE wait point:
// 13 producer lanes (even U) ds_write their packed word; all lanes read the
// 13 words back as 3x ds_read_b128 + 1x ds_read_b32 (same-address broadcast,
// conflict-free). Same-wave DS ops execute in order -> no barrier needed.
// This replaces 13 readlanes (R5) / 13 bpermutes (R6, regressed).
__global__ __launch_bounds__(64)
__attribute__((amdgpu_waves_per_eu(1, 1)))
void lstm_kernel(
    const float* __restrict__ x,
    const float* __restrict__ W_ih,
    const float* __restrict__ W_hh,
    const float* __restrict__ b_ih,
    const float* __restrict__ b_hh,
    const float* __restrict__ W_lin,
    const float* __restrict__ b_lin,
    float* __restrict__ out)
{
    const int lane = threadIdx.x;
    const int b    = blockIdx.x;

    __shared__ __align__(16) int hxw[32];  // words 0..12 = packed h; 16..31 scratch
    __shared__ float pp[64][29];           // deferred output partials

    const bool U  = (lane >= 32);
    const int  j  = lane & 31;
    const int  jj = (j < HIDDEN) ? j : 0;          // clamp idle lanes to a harmless row
    const bool hv = (j < HIDDEN);

    const int r1 = U ? (HIDDEN + jj) : jj;                     // f : i  (sigmoid)
    const int r2 = U ? (3 * HIDDEN + jj) : (2 * HIDDEN + jj);  // o : g

    const float LOG2E = 1.4426950408889634f;
    const float s1 = -LOG2E;                       // sigmoid pre-scale
    const float s2 = U ? -LOG2E : (-2.0f * LOG2E); // o: sigmoid, g: tanh(=sig(2x) form)

    // fold scales into weights, pad k=25 with 0, pack to f16 pairs
    float w1[26], w2[26];
    #pragma unroll
    for (int k = 0; k < HIDDEN; ++k) {
        w1[k] = W_hh[r1 * HIDDEN + k] * s1;
        w2[k] = W_hh[r2 * HIDDEN + k] * s2;
    }
    w1[25] = 0.0f; w2[25] = 0.0f;
    int W1p[13], W2p[13];
    #pragma unroll
    for (int m = 0; m < 13; ++m) {
        W1p[m] = __builtin_bit_cast(int, __builtin_amdgcn_cvt_pkrtz(w1[2*m], w1[2*m+1]));
        W2p[m] = __builtin_bit_cast(int, __builtin_amdgcn_cvt_pkrtz(w2[2*m], w2[2*m+1]));
    }
    float bias1 = (b_ih[r1] + b_hh[r1]) * s1;
    float bias2 = (b_ih[r2] + b_hh[r2]) * s2;
    float wi1   = W_ih[r1] * s1;
    float wi2   = W_ih[r2] * s2;

    // pin loop-invariants into VGPRs (defeat remat/spill)
    #pragma unroll
    for (int m = 0; m < 13; ++m) {
        asm volatile("" : "+v"(W1p[m]));
        asm volatile("" : "+v"(W2p[m]));
    }
    asm volatile("" : "+v"(bias1), "+v"(bias2), "+v"(wi1), "+v"(wi2));

    const float wlin  = (U && hv) ? W_lin[jj] : 0.0f;
    const float blin  = b_lin[0];
    const int   pcol  = (U && hv) ? jj : 26;       // inactive lanes dump into unused col

    // h-exchange write slot: even U lanes (j=0,2,..,24) own words 0..12;
    // everyone else dumps into the scratch half.
    const bool prod  = U && hv && !(j & 1);
    const int  wword = prod ? (j >> 1) : (16 + (lane & 15));

    if (lane < 32) hxw[lane] = 0;                  // h(0) = 0
    __syncthreads();

    float cs = 0.0f;   // c' = -2log2e * c   (real on U lanes)
    float vh = 0.0f;   // h                  (real on U lanes)

    const float* xb = x + b;
    float xv = xb[(size_t)lane * BATCH];           // x[t=lane][b], staggered prefetch

    #pragma unroll 1
    for (int tb = 0; tb < SEQ_LEN; tb += 64) {
        float xv_next = 0.0f;
        if (tb + 64 < SEQ_LEN) xv_next = xb[(size_t)(tb + 64 + lane) * BATCH];

        #pragma unroll 4
        for (int tt = 0; tt < 64; ++tt) {
            // pack {h_j, h_{j^1}} as f16x2 (valid on even U lanes) and publish
            const int vhn = __builtin_amdgcn_mov_dpp(__float_as_int(vh), 0xB1, 0xF, 0xF, true);
            const int hpk = __builtin_bit_cast(int,
                __builtin_amdgcn_cvt_pkrtz(vh, __int_as_float(vhn)));
            hxw[wword] = hpk;                      // ds_write_b32 (in-order vs reads below)

            // read all 13 packed words back (same-address broadcast)
            int hw[13];
            {
                const int4* p = reinterpret_cast<const int4*>(&hxw[0]);
                int4 q0 = p[0], q1 = p[1], q2 = p[2];
                hw[0]=q0.x; hw[1]=q0.y; hw[2]=q0.z;  hw[3]=q0.w;
                hw[4]=q1.x; hw[5]=q1.y; hw[6]=q1.z;  hw[7]=q1.w;
                hw[8]=q2.x; hw[9]=q2.y; hw[10]=q2.z; hw[11]=q2.w;
                hw[12] = hxw[12];
            }

            // x-side affine (independent of h -> fills the LDS wait)
            const float xt = __int_as_float(__builtin_amdgcn_readlane(__float_as_int(xv), tt));
            float a1 = fmaf(xt, wi1, bias1);
            float a2 = fmaf(xt, wi2, bias2);

            float b1 = 0.0f, b2 = 0.0f;
            #pragma unroll
            for (int m = 0; m < 12; m += 2) {      // 4 independent dot2 chains
                a1 = fdot2i(W1p[m],     hw[m],     a1);
                b1 = fdot2i(W1p[m + 1], hw[m + 1], b1);
                a2 = fdot2i(W2p[m],     hw[m],     a2);
                b2 = fdot2i(W2p[m + 1], hw[m + 1], b2);
            }
            a1 = fdot2i(W1p[12], hw[12], a1) + b1;
            a2 = fdot2i(W2p[12], hw[12], a2) + b2;

            const float R1 = fast_rcp(1.0f + fast_exp2(a1));   // i (L) / f (U)
            const float R2 = fast_rcp(1.0f + fast_exp2(a2));   // sig(2zg) (L) / o (U)

            // L: igs = i * g * (-2log2e), where g = 2*R2 - 1
            const float Gp  = fmaf(R2, -4.0f * LOG2E, 2.0f * LOG2E);
            const float igs = R1 * Gp;
            const float igx = xswap32(igs);        // U lanes receive L's igs

            cs = fmaf(R1, cs, igx);                // c' = f*c' + (-2log2e)*i*g  (U)
            const float R3 = fast_rcp(1.0f + fast_exp2(cs));   // sig(2c) -> tanh(c)=2R3-1
            const float o2 = R2 + R2;              // 2o (off critical path)
            vh = fmaf(o2, R3, -R2);                // h = o*tanh(c) = 2o*R3 - o  (U)

            pp[tt][pcol] = vh * wlin;              // deferred output partial
        }
        __syncthreads();

        // reduce 64 timesteps of output partials; one store per lane
        float s = blin;
        #pragma unroll
        for (int k = 0; k < HIDDEN; ++k) s += pp[lane][k];
        out[(size_t)(tb + lane) * BATCH + b] = s;
        __syncthreads();

        xv = xv_next;
    }
}

extern "C" void kernel_launch(void* const* d_in, const int* in_sizes, int n_in,
                              void* d_out, int out_size, void* d_ws, size_t ws_size,
                              hipStream_t stream) {
    const float* x     = (const float*)d_in[0];
    const float* W_ih  = (const float*)d_in[1];
    const float* W_hh  = (const float*)d_in[2];
    const float* b_ih  = (const float*)d_in[3];
    const float* b_hh  = (const float*)d_in[4];
    const float* W_lin = (const float*)d_in[5];
    const float* b_lin = (const float*)d_in[6];
    float* outp = (float*)d_out;

    hipLaunchKernelGGL(lstm_kernel, dim3(BATCH), dim3(64), 0, stream,
                       x, W_ih, W_hh, b_ih, b_hh, W_lin, b_lin, outp);
}